// Round 8
// baseline (94.545 us; speedup 1.0000x reference)
//
#include <hip/hip_runtime.h>
#include <hip/hip_fp16.h>

// Problem: Topo_60653528154131
//   x:[256,3,256,25] f32, centres:[64,2] f32, sharpness:[64,2] f32 -> out:[64] f32
//
// Cost model (fitted R0-R7): dur_us = C + sum(kernel times); C ~= 65 us fixed
// (256MiB harness ws poison fill ~43us in-stream + launch/teardown). Kernels run
// at un-ramped clock -> serial cycles and BLOCK BARRIERS dominate tiny kernels.
// R7 confirmed: cutting k_mst 5->3 barriers/round gained ~15us vs R5.
//
// This round: k_mst hybrid rounds. Multi-wave (3-barrier) rounds only while
// n > 64 (typically one round); once n <= 64 a SINGLE wave owns each round
// (1 row/lane full scan, hook, fold) with only wave_barrier()s — zero block
// barriers. Same deterministic Boruvka; deaths bit-identical (hook structure
// depends only on rowKeyS values, reproduced exactly by the direct scan).
//
//   K1 k_feat    : mean -> feat row n (parallel S1/S2) + Mp INF-init.
//   K2 k_dist    : light D2 row + DPP row-min key + inline feat minmax.
//   K3 k_contract: distributed Boruvka round-1 fold into Mp (R0-verified).
//   K4 k_mst     : hybrid rounds 2+ (see above), structure layer.
//
// ws layout:
//   featG [6656] f32 @ 0      (stride 26)
//   mm    [2]    u32 @ 26624
//   rowKeyG[256] u32 @ 28672
//   deathsG[256] f32 @ 29696
//   ncdcG [2]    u32 @ 30720
//   D16  [65536] u16 @ 65536
//   Mp   [128*132] u32 @ 196608

#define WS_FEAT 0
#define WS_MM   26624
#define WS_RK   28672
#define WS_DTH  29696
#define WS_NCDC 30720
#define WS_D16  65536
#define WS_MP   196608

#define INF32 0xFFFFFFFFu
#define SA 132   // u32 stride, buffer A (cap 128 rows)
#define SB 68    // u32 stride, buffer B (cap 64 rows)
#define OFF_B (128 * SA)

// ---------------- K1: mean + feat row + Mp INF-init ----------------
__global__ void __launch_bounds__(256) k_feat(const float* __restrict__ x,
                                              float* __restrict__ featG,
                                              unsigned int* __restrict__ Mp) {
    __shared__ float sums[25];
    __shared__ float mrow[25];
    const int n = blockIdx.x;
    const int tid = threadIdx.x;
    if (tid < 66) Mp[n * 66 + tid] = INF32;   // 256*66 = 16896 = 128*132 exactly
    if (tid < 25) sums[tid] = 0.0f;
    __syncthreads();
    if (tid < 200) {
        const float* base = x + (long)n * 19200 + 4 * tid;
        float a0 = 0.f, a1 = 0.f, a2 = 0.f, a3 = 0.f;
        #pragma unroll
        for (int i = 0; i < 24; ++i) {
            float4 v = *reinterpret_cast<const float4*>(base + 800 * i);
            a0 += v.x; a1 += v.y; a2 += v.z; a3 += v.w;
        }
        const int v0 = (4 * tid) % 25;
        atomicAdd(&sums[v0], a0);
        atomicAdd(&sums[(v0 + 1) % 25], a1);
        atomicAdd(&sums[(v0 + 2) % 25], a2);
        atomicAdd(&sums[(v0 + 3) % 25], a3);
    }
    __syncthreads();
    if (tid < 25) mrow[tid] = sums[tid] * (1.0f / 768.0f);
    __syncthreads();
    if (tid < 25) {
        // parallel redundant S1/S2 (same FP order as serial -> bit-identical)
        float S1 = 0.f, S2 = 0.f;
        #pragma unroll
        for (int v = 0; v < 25; ++v) {
            const float mv = mrow[v];
            S1 += mv; S2 += mv * mv;
        }
        const float r = mrow[tid];
        float q = S2 - 2.f * r * S1 + 25.f * r * r;
        q = fmaxf(q, 0.f);
        featG[n * 26 + tid] = sqrtf(q);
    }
}

// wave64 min-reduce step via DPP: result in lane 63
template <int CTRL>
__device__ __forceinline__ unsigned int dpp_min_step(unsigned int v) {
    unsigned int t = (unsigned int)__builtin_amdgcn_update_dpp(
        (int)0xFFFFFFFF, (int)v, CTRL, 0xF, 0xF, false);
    return (t < v) ? t : v;
}

// ---------------- K2: D2 row + row-min key + minmax (blk0 -> mm) ----------------
__global__ void __launch_bounds__(256) k_dist(const float* __restrict__ featG,
                                              unsigned short* __restrict__ D16,
                                              unsigned int* __restrict__ rowKeyG,
                                              unsigned int* __restrict__ mm) {
    __shared__ float featS[6656];          // stride 26
    __shared__ unsigned int wred[4];
    __shared__ unsigned int bmn, bmx;
    const int i = blockIdx.x;
    const int t = threadIdx.x;
    if (t == 0) { bmn = 0x7F800000u; bmx = 0u; }
    #pragma unroll
    for (int it = 0; it < 7; ++it) {
        const int o = it * 256 + t;
        if (o < 1664) reinterpret_cast<float4*>(featS)[o] =
            reinterpret_cast<const float4*>(featG)[o];
    }
    __syncthreads();
    float fi[25];
    #pragma unroll
    for (int v = 0; v < 25; ++v) fi[v] = featS[i * 26 + v];   // broadcast reads
    float s = 0.f, fmn = 1e30f, fmx = -1e30f;
    #pragma unroll
    for (int v = 0; v < 25; ++v) {
        const float ft = featS[t * 26 + v];        // row t (thread-owned)
        const float d = fi[v] - ft;
        s += d * d;
        fmn = fminf(fmn, ft); fmx = fmaxf(fmx, ft);
    }
    if (i == 0) {   // feat >= 0 -> uint compare == float compare
        atomicMin(&bmn, __float_as_uint(fmn));
        atomicMax(&bmx, __float_as_uint(fmx));
    }
    const unsigned int w16 = (unsigned int)__half_as_ushort(__float2half(s));
    D16[i * 256 + t] = (unsigned short)w16;
    const unsigned int lo = (t < i) ? t : i, hi = (t < i) ? i : t;
    unsigned int key = (t == i) ? INF32 : ((w16 << 16) | (lo << 8) | hi);
    key = dpp_min_step<0x111>(key);
    key = dpp_min_step<0x112>(key);
    key = dpp_min_step<0x114>(key);
    key = dpp_min_step<0x118>(key);
    key = dpp_min_step<0x142>(key);
    key = dpp_min_step<0x143>(key);
    if ((t & 63) == 63) wred[t >> 6] = key;
    __syncthreads();
    if (t == 0) {
        const unsigned int b0 = wred[0] < wred[1] ? wred[0] : wred[1];
        const unsigned int b1 = wred[2] < wred[3] ? wred[2] : wred[3];
        rowKeyG[i] = b0 < b1 ? b0 : b1;
        if (i == 0) { mm[0] = bmn; mm[1] = bmx; }
    }
}

// ---------------- wave0 Boruvka phase (R0-verified; returns nc, uniform) -------
template <bool RECORD>
__device__ __forceinline__ unsigned int wave0_phase(int n, int lane,
        unsigned int* rowKeyS, unsigned char* parentS, unsigned char* newidS,
        unsigned char* cmapS, float* deaths, unsigned int* ncS, unsigned int* dcS) {
    unsigned int par[4];
    #pragma unroll
    for (int s = 0; s < 4; ++s) {         // hook
        const int i = lane + 64 * s;
        if (i < n) {
            const unsigned int rk = rowKeyS[i];
            const unsigned int u = (rk >> 8) & 0xFFu, v = rk & 0xFFu;
            unsigned int p = (u == (unsigned int)i) ? v : u;
            if (rk == INF32) p = (unsigned int)i;
            par[s] = p;
            parentS[i] = (unsigned char)p;
        }
    }
    #pragma unroll
    for (int s = 0; s < 4; ++s) {         // break mutual 2-cycles
        const int i = lane + 64 * s;
        if (i < n) {
            const unsigned int p = par[s];
            if (p != (unsigned int)i) {
                if (parentS[p] == (unsigned char)i && (unsigned int)i < p) {
                    parentS[i] = (unsigned char)i;   // winner stays root
                } else if (RECORD) {
                    const unsigned int d = atomicAdd(dcS, 1u);
                    const unsigned int rk = rowKeyS[i];
                    deaths[d] = sqrtf(__half2float(__ushort_as_half(
                        (unsigned short)(rk >> 16))));
                }
            }
        }
    }
    for (;;) {                            // async pointer jump
        bool ch = false;
        #pragma unroll
        for (int s = 0; s < 4; ++s) {
            const int i = lane + 64 * s;
            if (i < n) {
                const unsigned char p0 = parentS[i];
                const unsigned char np = parentS[p0];
                if (np != p0) { ch = true; parentS[i] = np; }
            }
        }
        if (__ballot(ch) == 0ull) break;
    }
    bool isr[4];
    #pragma unroll
    for (int s = 0; s < 4; ++s) {
        const int i = lane + 64 * s;
        isr[s] = (i < n) && (parentS[i] == (unsigned char)i);
    }
    unsigned int base = 0;
    const unsigned long long below = (1ull << lane) - 1ull;
    #pragma unroll
    for (int s = 0; s < 4; ++s) {
        const unsigned long long mask = __ballot(isr[s]);   // uniform execution
        if (isr[s]) {
            const int i = lane + 64 * s;
            newidS[i] = (unsigned char)(base + __popcll(mask & below));
        }
        base += (unsigned int)__popcll(mask);
    }
    if (lane == 0) *ncS = base;
    #pragma unroll
    for (int s = 0; s < 4; ++s) {
        const int i = lane + 64 * s;
        if (i < n) cmapS[i] = newidS[parentS[i]];
    }
    return base;          // uniform across lanes (ballot-derived)
}

// ---------------- K3: distributed round-1 contraction (R0-verified) ----------
__global__ void __launch_bounds__(256) k_contract(const unsigned short* __restrict__ D16g,
                                                  const unsigned int* __restrict__ rowKeyG,
                                                  unsigned int* __restrict__ Mp,
                                                  float* __restrict__ deathsG,
                                                  unsigned int* __restrict__ ncdcG) {
    __shared__ unsigned int rowKeyS[256];
    __shared__ unsigned char parentS[256], newidS[256], cmapS[256];
    __shared__ unsigned int ncS, dcS;
    __shared__ float deathsS[256];
    const int tid = threadIdx.x;
    const int b = blockIdx.x;
    rowKeyS[tid] = rowKeyG[tid];
    if (tid == 0) dcS = 0;
    __syncthreads();
    if (tid < 64) {
        if (b == 0)
            wave0_phase<true>(256, tid, rowKeyS, parentS, newidS, cmapS,
                              deathsS, &ncS, &dcS);
        else
            wave0_phase<false>(256, tid, rowKeyS, parentS, newidS, cmapS,
                               nullptr, &ncS, nullptr);
    }
    __syncthreads();
    if (b == 0) {   // publish round-1 deaths + counts (deterministic multiset)
        if (tid < dcS) deathsG[tid] = deathsS[tid];
        if (tid == 0) { ncdcG[0] = ncS; ncdcG[1] = dcS; }
    }
    // fold row b into Mp via global atomicMin (distributed across 256 CUs)
    const unsigned int ca = cmapS[b];
    const unsigned int cb = cmapS[tid];
    if (ca != cb) {
        const unsigned int w16 = (unsigned int)D16g[b * 256 + tid];
        const unsigned int lo = ca < cb ? ca : cb;
        const unsigned int hi = ca < cb ? cb : ca;
        atomicMin(&Mp[ca * SA + cb], (w16 << 16) | (lo << 8) | hi);
    }
}

// ---------------- K4: hybrid Boruvka rounds 2+ + structure ----------------
__global__ void __launch_bounds__(1024) k_mst(const unsigned int* __restrict__ Mp,
                                              const float* __restrict__ deathsG,
                                              const unsigned int* __restrict__ ncdcG,
                                              const unsigned int* __restrict__ mm,
                                              const float* __restrict__ centres,
                                              const float* __restrict__ sharp,
                                              float* __restrict__ out) {
    __shared__ unsigned int Mb[128 * SA + 64 * SB];   // 84.5 KB ping-pong
    __shared__ unsigned int rowKeyS[128];             // rounds 2+: n <= 128
    __shared__ unsigned char parentS[128], newidS[128], cmapS[128];
    __shared__ unsigned int ncS, dcS;
    __shared__ float deaths[256];
    __shared__ float outpart[1024];
    const int tid = threadIdx.x;

    if (tid == 0) { ncS = ncdcG[0]; dcS = ncdcG[1]; }
    if (tid < 256) deaths[tid] = deathsG[tid];   // only [0,dcS) meaningful
    if (tid < 128) rowKeyS[tid] = INF32;         // pre-init for multi-wave round
    // fixed-size vectorized load of full Mp region (4224 uint4 = 128*SA u32):
    // no ncS dependency -> single prologue barrier
    for (int idx = tid; idx < 4224; idx += 1024)
        reinterpret_cast<uint4*>(Mb)[idx] =
            reinterpret_cast<const uint4*>(Mp)[idx];
    __syncthreads();
    int n = (int)ncS;

    int srcOff = 0, srcStr = SA, dstOff = OFF_B, dstStr = SB;

    // ---- multi-wave rounds (3 barriers each) only while n > 64 ----
    for (int round = 0; round < 12 && n > 64; ++round) {
        // phase A: row-min scan (8 threads/row) + dst INF-init (disjoint regions)
        if (tid < 8 * n) {
            const int a = tid >> 3, sub = tid & 7;
            const unsigned int* row = &Mb[srcOff + a * srcStr];
            unsigned int best = INF32;
            for (int b2 = sub; b2 < n; b2 += 8) {
                const unsigned int v = row[b2];
                best = v < best ? v : best;
            }
            if (best != INF32) atomicMin(&rowKeyS[a], best);
        }
        const int dstCap = (n >> 1) * dstStr;    // nc <= n/2 (no singletons)
        for (int w = tid; w < dstCap; w += 1024) Mb[dstOff + w] = INF32;
        __syncthreads();
        // phase B: hook + renumber (wave 0)
        if (tid < 64)
            wave0_phase<true>(n, tid, rowKeyS, parentS, newidS, cmapS,
                              deaths, &ncS, &dcS);
        __syncthreads();
        const int nc = (int)ncS;
        if (nc <= 1) { n = nc; break; }
        // phase C: fold src -> dst + next-round rowKey INF-init
        if (tid < 8 * n) {
            const int a = tid >> 3, sub = tid & 7;
            const unsigned int ca = cmapS[a];
            const unsigned int* row = &Mb[srcOff + a * srcStr];
            for (int b2 = sub; b2 < n; b2 += 8) {
                const unsigned int cb = cmapS[b2];
                const unsigned int v = row[b2];
                if (ca != cb && v != INF32) {
                    const unsigned int lo = ca < cb ? ca : cb;
                    const unsigned int hi = ca < cb ? cb : ca;
                    atomicMin(&Mb[dstOff + ca * dstStr + cb],
                              (v & 0xFFFF0000u) | (lo << 8) | hi);
                }
            }
        }
        for (int j = tid; j < (n >> 1); j += 1024) rowKeyS[j] = INF32;
        __syncthreads();
        const int t1 = srcOff; srcOff = dstOff; dstOff = t1;
        const int t2 = srcStr; srcStr = dstStr; dstStr = t2;
        n = nc;
    }

    // ---- wave-0-only tail rounds (n <= 64): zero block barriers ----
    // Intra-wave LDS ordering (same-wave write->read) is the same assumption
    // wave0_phase itself relies on; wave_barrier pins compiler ordering.
    if (tid < 64 && n > 1) {
        const int lane = tid;
        for (int round = 0; round < 12 && n > 1; ++round) {
            if (lane < n) {               // full-row scan, direct write (no atomic)
                const unsigned int* row = &Mb[srcOff + lane * srcStr];
                unsigned int best = INF32;
                for (int b2 = 0; b2 < n; ++b2) {
                    const unsigned int v = row[b2];
                    best = v < best ? v : best;
                }
                rowKeyS[lane] = best;
            }
            __builtin_amdgcn_wave_barrier();
            const unsigned int nc = wave0_phase<true>(n, lane, rowKeyS, parentS,
                                                      newidS, cmapS, deaths,
                                                      &ncS, &dcS);
            __builtin_amdgcn_wave_barrier();
            if (nc <= 1) break;
            for (int w = lane; w < (int)nc * dstStr; w += 64)
                Mb[dstOff + w] = INF32;
            __builtin_amdgcn_wave_barrier();
            if (lane < n) {               // fold row lane
                const unsigned int ca = cmapS[lane];
                const unsigned int* row = &Mb[srcOff + lane * srcStr];
                for (int b2 = 0; b2 < n; ++b2) {
                    const unsigned int cb = cmapS[b2];
                    const unsigned int v = row[b2];
                    if (ca != cb && v != INF32) {
                        const unsigned int lo = ca < cb ? ca : cb;
                        const unsigned int hi = ca < cb ? cb : ca;
                        atomicMin(&Mb[dstOff + ca * dstStr + cb],
                                  (v & 0xFFFF0000u) | (lo << 8) | hi);
                    }
                }
            }
            __builtin_amdgcn_wave_barrier();
            const int t1 = srcOff; srcOff = dstOff; dstOff = t1;
            const int t2 = srcStr; srcStr = dstStr; dstStr = t2;
            n = (int)nc;
        }
    }
    __syncthreads();

    // structure-element layer (verified 16-partial form)
    const float mn = __uint_as_float(mm[0]);
    const float mx = __uint_as_float(mm[1]);
    const float inv = 1.0f / (mx - mn);
    const int k = tid & 63;
    const int part = tid >> 6;
    const float c0 = centres[2 * k], c1 = centres[2 * k + 1];
    const float s0 = sharp[2 * k],   s1 = sharp[2 * k + 1];
    const float t0 = c0 * c0 * s0 * s0;
    const float s1sq = s1 * s1;
    float acc = 0.f;
    for (int idx = part; idx < 255; idx += 16) {
        const float d = deaths[idx] * inv - c1;
        acc += __expf(-(t0 + d * d * s1sq));
    }
    outpart[tid] = acc;
    __syncthreads();
    if (tid < 64) {
        float s = 0.f;
        #pragma unroll
        for (int pp = 0; pp < 16; ++pp) s += outpart[tid + 64 * pp];
        out[tid] = s;
    }
}

extern "C" void kernel_launch(void* const* d_in, const int* in_sizes, int n_in,
                              void* d_out, int out_size, void* d_ws, size_t ws_size,
                              hipStream_t stream) {
    const float* x       = (const float*)d_in[0];
    const float* centres = (const float*)d_in[1];
    const float* sharp   = (const float*)d_in[2];
    float* out = (float*)d_out;
    char* ws = (char*)d_ws;
    float*          featG = (float*)(ws + WS_FEAT);
    unsigned int*   mm    = (unsigned int*)(ws + WS_MM);
    unsigned int*   rk    = (unsigned int*)(ws + WS_RK);
    float*          dth   = (float*)(ws + WS_DTH);
    unsigned int*   ncdc  = (unsigned int*)(ws + WS_NCDC);
    unsigned short* D16   = (unsigned short*)(ws + WS_D16);
    unsigned int*   Mp    = (unsigned int*)(ws + WS_MP);

    k_feat<<<256, 256, 0, stream>>>(x, featG, Mp);
    k_dist<<<256, 256, 0, stream>>>(featG, D16, rk, mm);
    k_contract<<<256, 256, 0, stream>>>(D16, rk, Mp, dth, ncdc);
    k_mst<<<1, 1024, 0, stream>>>(Mp, dth, ncdc, mm, centres, sharp, out);
}

// Round 9
// 92.720 us; speedup vs baseline: 1.0197x; 1.0197x over previous
//
#include <hip/hip_runtime.h>
#include <hip/hip_fp16.h>

// Problem: Topo_60653528154131
//   x:[256,3,256,25] f32, centres:[64,2] f32, sharpness:[64,2] f32 -> out:[64] f32
//
// Cost model (fitted R0-R8): dur_us = B + L*nkernels + sum(kernel times);
// B ~= 49-57 us (256MiB harness poison fill ~43us + teardown), L ~= 7.6 us per
// launch, sum(kernels) ~= 12 us at 4 kernels. Kernel count is the lever now.
//
// 3-kernel pipeline:
//   K1 k_feat : mean -> feat row n (parallel S1/S2) + Mp INF-init + done=0.
//   K2 k_dist : light D2 row + DPP row-min key + inline feat minmax -> mm.
//   K3 k_cmst : 256 blocks x 1024. All blocks: deterministic Boruvka round-1
//               replay from rowKeyG (identical cmap everywhere), fold OWN row of
//               D16 into Mp via device-scope atomicMin, s_waitcnt vmcnt(0),
//               atomicAdd(done). Blocks != 0 exit. Block 0: spin done==256
//               (acquire/agent — one-directional wait, NOT a grid barrier; all
//               256 blocks co-resident at 1 block/CU so no dispatch deadlock,
//               bounded spin guard), load Mp via agent-scope atomic loads
//               (stale-L1/L2 safe), R7-verified 3-barrier Boruvka rounds 2+,
//               structure-element layer. deaths/nc stay in LDS (no globals).
//
// ws layout:
//   featG [6656] f32 @ 0      (stride 26)
//   mm    [2]    u32 @ 26624
//   rowKeyG[256] u32 @ 28672
//   doneG [1]    u32 @ 30720
//   D16  [65536] u16 @ 65536
//   Mp   [128*132] u32 @ 196608

#define WS_FEAT 0
#define WS_MM   26624
#define WS_RK   28672
#define WS_DONE 30720
#define WS_D16  65536
#define WS_MP   196608

#define INF32 0xFFFFFFFFu
#define SA 132   // u32 stride, buffer A (cap 128 rows)
#define SB 68    // u32 stride, buffer B (cap 64 rows)
#define OFF_B (128 * SA)

// ---------------- K1: mean + feat row + Mp INF-init + done=0 ----------------
__global__ void __launch_bounds__(256) k_feat(const float* __restrict__ x,
                                              float* __restrict__ featG,
                                              unsigned int* __restrict__ Mp,
                                              unsigned int* __restrict__ doneG) {
    __shared__ float sums[25];
    __shared__ float mrow[25];
    const int n = blockIdx.x;
    const int tid = threadIdx.x;
    if (tid < 66) Mp[n * 66 + tid] = INF32;   // 256*66 = 16896 = 128*132 exactly
    if (n == 0 && tid == 0) *doneG = 0u;      // reset completion counter
    if (tid < 25) sums[tid] = 0.0f;
    __syncthreads();
    if (tid < 200) {
        const float* base = x + (long)n * 19200 + 4 * tid;
        float a0 = 0.f, a1 = 0.f, a2 = 0.f, a3 = 0.f;
        #pragma unroll
        for (int i = 0; i < 24; ++i) {
            float4 v = *reinterpret_cast<const float4*>(base + 800 * i);
            a0 += v.x; a1 += v.y; a2 += v.z; a3 += v.w;
        }
        const int v0 = (4 * tid) % 25;
        atomicAdd(&sums[v0], a0);
        atomicAdd(&sums[(v0 + 1) % 25], a1);
        atomicAdd(&sums[(v0 + 2) % 25], a2);
        atomicAdd(&sums[(v0 + 3) % 25], a3);
    }
    __syncthreads();
    if (tid < 25) mrow[tid] = sums[tid] * (1.0f / 768.0f);
    __syncthreads();
    if (tid < 25) {
        // parallel redundant S1/S2 (same FP order as serial -> bit-identical)
        float S1 = 0.f, S2 = 0.f;
        #pragma unroll
        for (int v = 0; v < 25; ++v) {
            const float mv = mrow[v];
            S1 += mv; S2 += mv * mv;
        }
        const float r = mrow[tid];
        float q = S2 - 2.f * r * S1 + 25.f * r * r;
        q = fmaxf(q, 0.f);
        featG[n * 26 + tid] = sqrtf(q);
    }
}

// wave64 min-reduce step via DPP: result in lane 63
template <int CTRL>
__device__ __forceinline__ unsigned int dpp_min_step(unsigned int v) {
    unsigned int t = (unsigned int)__builtin_amdgcn_update_dpp(
        (int)0xFFFFFFFF, (int)v, CTRL, 0xF, 0xF, false);
    return (t < v) ? t : v;
}

// ---------------- K2: D2 row + row-min key + minmax (blk0 -> mm) ----------------
__global__ void __launch_bounds__(256) k_dist(const float* __restrict__ featG,
                                              unsigned short* __restrict__ D16,
                                              unsigned int* __restrict__ rowKeyG,
                                              unsigned int* __restrict__ mm) {
    __shared__ float featS[6656];          // stride 26
    __shared__ unsigned int wred[4];
    __shared__ unsigned int bmn, bmx;
    const int i = blockIdx.x;
    const int t = threadIdx.x;
    if (t == 0) { bmn = 0x7F800000u; bmx = 0u; }
    #pragma unroll
    for (int it = 0; it < 7; ++it) {
        const int o = it * 256 + t;
        if (o < 1664) reinterpret_cast<float4*>(featS)[o] =
            reinterpret_cast<const float4*>(featG)[o];
    }
    __syncthreads();
    float fi[25];
    #pragma unroll
    for (int v = 0; v < 25; ++v) fi[v] = featS[i * 26 + v];   // broadcast reads
    float s = 0.f, fmn = 1e30f, fmx = -1e30f;
    #pragma unroll
    for (int v = 0; v < 25; ++v) {
        const float ft = featS[t * 26 + v];        // row t (thread-owned)
        const float d = fi[v] - ft;
        s += d * d;
        fmn = fminf(fmn, ft); fmx = fmaxf(fmx, ft);
    }
    if (i == 0) {   // feat >= 0 -> uint compare == float compare
        atomicMin(&bmn, __float_as_uint(fmn));
        atomicMax(&bmx, __float_as_uint(fmx));
    }
    const unsigned int w16 = (unsigned int)__half_as_ushort(__float2half(s));
    D16[i * 256 + t] = (unsigned short)w16;
    const unsigned int lo = (t < i) ? t : i, hi = (t < i) ? i : t;
    unsigned int key = (t == i) ? INF32 : ((w16 << 16) | (lo << 8) | hi);
    key = dpp_min_step<0x111>(key);
    key = dpp_min_step<0x112>(key);
    key = dpp_min_step<0x114>(key);
    key = dpp_min_step<0x118>(key);
    key = dpp_min_step<0x142>(key);
    key = dpp_min_step<0x143>(key);
    if ((t & 63) == 63) wred[t >> 6] = key;
    __syncthreads();
    if (t == 0) {
        const unsigned int b0 = wred[0] < wred[1] ? wred[0] : wred[1];
        const unsigned int b1 = wred[2] < wred[3] ? wred[2] : wred[3];
        rowKeyG[i] = b0 < b1 ? b0 : b1;
        if (i == 0) { mm[0] = bmn; mm[1] = bmx; }
    }
}

// ---------------- wave0 Boruvka phase (R0-verified) ----------------
template <bool RECORD>
__device__ __forceinline__ void wave0_phase(int n, int lane,
        unsigned int* rowKeyS, unsigned char* parentS, unsigned char* newidS,
        unsigned char* cmapS, float* deaths, unsigned int* ncS, unsigned int* dcS) {
    unsigned int par[4];
    #pragma unroll
    for (int s = 0; s < 4; ++s) {         // hook
        const int i = lane + 64 * s;
        if (i < n) {
            const unsigned int rk = rowKeyS[i];
            const unsigned int u = (rk >> 8) & 0xFFu, v = rk & 0xFFu;
            unsigned int p = (u == (unsigned int)i) ? v : u;
            if (rk == INF32) p = (unsigned int)i;
            par[s] = p;
            parentS[i] = (unsigned char)p;
        }
    }
    #pragma unroll
    for (int s = 0; s < 4; ++s) {         // break mutual 2-cycles
        const int i = lane + 64 * s;
        if (i < n) {
            const unsigned int p = par[s];
            if (p != (unsigned int)i) {
                if (parentS[p] == (unsigned char)i && (unsigned int)i < p) {
                    parentS[i] = (unsigned char)i;   // winner stays root
                } else if (RECORD) {
                    const unsigned int d = atomicAdd(dcS, 1u);
                    const unsigned int rk = rowKeyS[i];
                    deaths[d] = sqrtf(__half2float(__ushort_as_half(
                        (unsigned short)(rk >> 16))));
                }
            }
        }
    }
    for (;;) {                            // async pointer jump
        bool ch = false;
        #pragma unroll
        for (int s = 0; s < 4; ++s) {
            const int i = lane + 64 * s;
            if (i < n) {
                const unsigned char p0 = parentS[i];
                const unsigned char np = parentS[p0];
                if (np != p0) { ch = true; parentS[i] = np; }
            }
        }
        if (__ballot(ch) == 0ull) break;
    }
    bool isr[4];
    #pragma unroll
    for (int s = 0; s < 4; ++s) {
        const int i = lane + 64 * s;
        isr[s] = (i < n) && (parentS[i] == (unsigned char)i);
    }
    unsigned int base = 0;
    const unsigned long long below = (1ull << lane) - 1ull;
    #pragma unroll
    for (int s = 0; s < 4; ++s) {
        const unsigned long long mask = __ballot(isr[s]);   // uniform execution
        if (isr[s]) {
            const int i = lane + 64 * s;
            newidS[i] = (unsigned char)(base + __popcll(mask & below));
        }
        base += (unsigned int)__popcll(mask);
    }
    if (lane == 0) *ncS = base;
    #pragma unroll
    for (int s = 0; s < 4; ++s) {
        const int i = lane + 64 * s;
        if (i < n) cmapS[i] = newidS[parentS[i]];
    }
}

// ---------------- K3: fused contract + rounds + structure ----------------
__global__ void __launch_bounds__(1024) k_cmst(const unsigned short* __restrict__ D16g,
                                               const unsigned int* __restrict__ rowKeyG,
                                               unsigned int* __restrict__ Mp,
                                               unsigned int* __restrict__ doneG,
                                               const unsigned int* __restrict__ mm,
                                               const float* __restrict__ centres,
                                               const float* __restrict__ sharp,
                                               float* __restrict__ out) {
    __shared__ unsigned int Mb[128 * SA + 64 * SB];   // 84.5 KB ping-pong
    __shared__ unsigned int rowKeyS[256];
    __shared__ unsigned char parentS[256], newidS[256], cmapS[256];
    __shared__ unsigned int ncS, dcS;
    __shared__ float deaths[256];
    __shared__ float outpart[1024];
    const int tid = threadIdx.x;
    const int b = blockIdx.x;

    // ---- phase 1 (all 256 blocks): round-1 replay + distributed fold ----
    if (tid < 256) rowKeyS[tid] = rowKeyG[tid];
    if (tid == 0) dcS = 0;
    __syncthreads();
    if (tid < 64) {
        if (b == 0)
            wave0_phase<true>(256, tid, rowKeyS, parentS, newidS, cmapS,
                              deaths, &ncS, &dcS);   // deaths persist in LDS
        else
            wave0_phase<false>(256, tid, rowKeyS, parentS, newidS, cmapS,
                               nullptr, &ncS, nullptr);
    }
    __syncthreads();
    if (tid < 256) {
        const unsigned int ca = cmapS[b];
        const unsigned int cb = cmapS[tid];
        if (ca != cb) {
            const unsigned int w16 = (unsigned int)D16g[b * 256 + tid];
            const unsigned int lo = ca < cb ? ca : cb;
            const unsigned int hi = ca < cb ? cb : ca;
            atomicMin(&Mp[ca * SA + cb], (w16 << 16) | (lo << 8) | hi);
        }
    }
    // ensure this block's atomicMins have COMPLETED (not just issued) before
    // signalling: vmcnt(0) drains them to the coherent point.
    asm volatile("s_waitcnt vmcnt(0)" ::: "memory");
    __syncthreads();
    if (tid == 0)
        __hip_atomic_fetch_add(doneG, 1u, __ATOMIC_RELEASE,
                               __HIP_MEMORY_SCOPE_AGENT);
    if (b != 0) return;

    // ---- block 0 only: wait for all folds (one-directional, bounded) ----
    if (tid == 0) {
        unsigned int guard = 0;
        while (__hip_atomic_load(doneG, __ATOMIC_ACQUIRE,
                                 __HIP_MEMORY_SCOPE_AGENT) < 256u) {
            __builtin_amdgcn_s_sleep(1);
            if (++guard > (1u << 22)) break;   // fail clean, never hang
        }
    }
    __syncthreads();

    // load Mp -> Mb via agent-scope atomic loads (bypass possibly-stale L1/L2;
    // remote XCDs' atomicMin results live at the coherent point)
    for (int idx = tid; idx < 128 * SA; idx += 1024)
        Mb[idx] = __hip_atomic_load(&Mp[idx], __ATOMIC_RELAXED,
                                    __HIP_MEMORY_SCOPE_AGENT);
    if (tid < 128) rowKeyS[tid] = INF32;         // pre-init for first round
    __syncthreads();
    int n = (int)ncS;                            // from this block's replay

    // ---- R7-verified rounds 2+ : 3 barriers per round ----
    int srcOff = 0, srcStr = SA, dstOff = OFF_B, dstStr = SB;
    for (int round = 0; round < 12 && n > 1; ++round) {
        // phase A: row-min scan (8 threads/row) + dst INF-init (disjoint)
        if (tid < 8 * n) {
            const int a = tid >> 3, sub = tid & 7;
            const unsigned int* row = &Mb[srcOff + a * srcStr];
            unsigned int best = INF32;
            for (int b2 = sub; b2 < n; b2 += 8) {
                const unsigned int v = row[b2];
                best = v < best ? v : best;
            }
            if (best != INF32) atomicMin(&rowKeyS[a], best);
        }
        const int dstCap = (n >> 1) * dstStr;    // nc <= n/2 (no singletons)
        for (int w = tid; w < dstCap; w += 1024) Mb[dstOff + w] = INF32;
        __syncthreads();
        // phase B: hook + renumber (wave 0)
        if (tid < 64)
            wave0_phase<true>(n, tid, rowKeyS, parentS, newidS, cmapS,
                              deaths, &ncS, &dcS);
        __syncthreads();
        const int nc = (int)ncS;
        if (nc <= 1) break;               // deaths complete
        // phase C: fold src -> dst + next-round rowKey INF-init
        if (tid < 8 * n) {
            const int a = tid >> 3, sub = tid & 7;
            const unsigned int ca = cmapS[a];
            const unsigned int* row = &Mb[srcOff + a * srcStr];
            for (int b2 = sub; b2 < n; b2 += 8) {
                const unsigned int cb = cmapS[b2];
                const unsigned int v = row[b2];
                if (ca != cb && v != INF32) {
                    const unsigned int lo = ca < cb ? ca : cb;
                    const unsigned int hi = ca < cb ? cb : ca;
                    atomicMin(&Mb[dstOff + ca * dstStr + cb],
                              (v & 0xFFFF0000u) | (lo << 8) | hi);
                }
            }
        }
        for (int j = tid; j < (n >> 1); j += 1024) rowKeyS[j] = INF32;
        __syncthreads();
        const int t1 = srcOff; srcOff = dstOff; dstOff = t1;
        const int t2 = srcStr; srcStr = dstStr; dstStr = t2;
        n = nc;
    }

    // ---- structure-element layer (verified 16-partial form) ----
    const float mn = __uint_as_float(mm[0]);
    const float mx = __uint_as_float(mm[1]);
    const float inv = 1.0f / (mx - mn);
    const int k = tid & 63;
    const int part = tid >> 6;
    const float c0 = centres[2 * k], c1 = centres[2 * k + 1];
    const float s0 = sharp[2 * k],   s1 = sharp[2 * k + 1];
    const float t0 = c0 * c0 * s0 * s0;
    const float s1sq = s1 * s1;
    float acc = 0.f;
    for (int idx = part; idx < 255; idx += 16) {
        const float d = deaths[idx] * inv - c1;
        acc += __expf(-(t0 + d * d * s1sq));
    }
    outpart[tid] = acc;
    __syncthreads();
    if (tid < 64) {
        float s = 0.f;
        #pragma unroll
        for (int pp = 0; pp < 16; ++pp) s += outpart[tid + 64 * pp];
        out[tid] = s;
    }
}

extern "C" void kernel_launch(void* const* d_in, const int* in_sizes, int n_in,
                              void* d_out, int out_size, void* d_ws, size_t ws_size,
                              hipStream_t stream) {
    const float* x       = (const float*)d_in[0];
    const float* centres = (const float*)d_in[1];
    const float* sharp   = (const float*)d_in[2];
    float* out = (float*)d_out;
    char* ws = (char*)d_ws;
    float*          featG = (float*)(ws + WS_FEAT);
    unsigned int*   mm    = (unsigned int*)(ws + WS_MM);
    unsigned int*   rk    = (unsigned int*)(ws + WS_RK);
    unsigned int*   done  = (unsigned int*)(ws + WS_DONE);
    unsigned short* D16   = (unsigned short*)(ws + WS_D16);
    unsigned int*   Mp    = (unsigned int*)(ws + WS_MP);

    k_feat<<<256, 256, 0, stream>>>(x, featG, Mp, done);
    k_dist<<<256, 256, 0, stream>>>(featG, D16, rk, mm);
    k_cmst<<<256, 1024, 0, stream>>>(D16, rk, Mp, done, mm, centres, sharp, out);
}